// Round 6
// baseline (353.995 us; speedup 1.0000x reference)
//
#include <hip/hip_runtime.h>

// MeanShift++ dense-grid, distinct-bin formulation, v4.
// Identity 1: ref pipeline == 5-tap triangular conv [1,2,3,2,1]^3 over per-bin
// sums/counts. Identity 2: result depends only on bin => per-step work is per
// OCCUPIED BIN (shrinking); per-point state via 1-tap lookups.
// v4: front end rebuilt as LDS-privatized counting sort (no global atomics):
//   histA (per-block LDS region hist) -> colscan -> regprefix -> scatterA
//   (bucket by region) -> binB (one block/region: LDS cell accumulate, plain
//   stores to A, fused compact -> E0 + PIdx point->entry table).
// PIdx turns upd1 and the final map into single gathers on ~1MB tables.

constexpr float BW   = 0.1f;
constexpr float TOL2 = 1e-6f;            // (1e-3)^2
constexpr int DIM  = 112, OFF = 56;      // bins in [-56,55]; |x|<5.6 covered
constexpr int DIM2 = DIM * DIM;
constexpr int CELLS = DIM * DIM * DIM;   // 1,404,928
constexpr int CLW = CELLS / 32;
constexpr int RDIM = 16, RC = 7;         // 16^3 regions of 7^3 cells (112=16*7)
constexpr int NREG = RDIM * RDIM * RDIM; // 4096
constexpr int RC3 = RC * RC * RC;        // 343
constexpr int NB_A = 128, BLK = 256;     // histA/scatterA must share partition

typedef float vf2 __attribute__((ext_vector_type(2)));

__device__ __forceinline__ int clampb(int v) { return v < 0 ? 0 : (v > DIM - 1 ? DIM - 1 : v); }
__device__ __forceinline__ int binf(float v) { return clampb((int)(v / BW) + OFF); }  // IEEE div+trunc == ref
__device__ __forceinline__ int flatb(int bx, int by, int bz) { return (bx * DIM + by) * DIM + bz; }
__device__ __forceinline__ int regOf(int bx, int by, int bz) {
    return ((bx / RC) * RDIM + (by / RC)) * RDIM + (bz / RC);
}
__device__ __forceinline__ int lcOf(int bx, int by, int bz) {
    return ((bx % RC) * RC + (by % RC)) * RC + (bz % RC);
}

__device__ __forceinline__ void pk_add(float* p, float a, float b) {
#if defined(__has_builtin) && __has_builtin(__builtin_amdgcn_global_atomic_fadd_v2f32)
    vf2 v = {a, b};
    __builtin_amdgcn_global_atomic_fadd_v2f32((vf2*)p, v);
#else
    atomicAdd(p, a);
    atomicAdd(p + 1, b);
#endif
}

// 5x5x5 triangular conv [1,2,3,2,1]^3; returns (nx,ny,nz, W=center count)
__device__ __forceinline__ float4 conv5(const float4* __restrict__ g, int bx, int by, int bz) {
    const float t[5] = {1.f, 2.f, 3.f, 2.f, 1.f};
    float sx = 0.f, sy = 0.f, sz = 0.f, sc = 0.f, W = 0.f;
    if (bx >= 2 && bx <= DIM - 3 && by >= 2 && by <= DIM - 3 && bz >= 2 && bz <= DIM - 3) {
        #pragma unroll
        for (int dx = 0; dx < 5; ++dx) {
            float wx = t[dx];
            #pragma unroll
            for (int dy = 0; dy < 5; ++dy) {
                float wxy = wx * t[dy];
                const float4* row = g + flatb(bx + dx - 2, by + dy - 2, bz - 2);
                #pragma unroll
                for (int dz = 0; dz < 5; ++dz) {
                    float w = wxy * t[dz];
                    float4 e = row[dz];
                    sx = fmaf(w, e.x, sx);
                    sy = fmaf(w, e.y, sy);
                    sz = fmaf(w, e.z, sz);
                    sc = fmaf(w, e.w, sc);
                    if (dx == 2 && dy == 2 && dz == 2) W = e.w;
                }
            }
        }
    } else {
        for (int dx = -2; dx <= 2; ++dx) {
            int ix = bx + dx; if ((unsigned)ix >= (unsigned)DIM) continue;
            float wx = t[dx + 2];
            for (int dy = -2; dy <= 2; ++dy) {
                int iy = by + dy; if ((unsigned)iy >= (unsigned)DIM) continue;
                float wxy = wx * t[dy + 2];
                for (int dz = -2; dz <= 2; ++dz) {
                    int iz = bz + dz; if ((unsigned)iz >= (unsigned)DIM) continue;
                    float w = wxy * t[dz + 2];
                    float4 e = g[flatb(ix, iy, iz)];
                    sx = fmaf(w, e.x, sx);
                    sy = fmaf(w, e.y, sy);
                    sz = fmaf(w, e.z, sz);
                    sc = fmaf(w, e.w, sc);
                    if (dx == 0 && dy == 0 && dz == 0) W = e.w;
                }
            }
        }
    }
    return make_float4(sx / sc, sy / sc, sz / sc, W);
}

// ---- pass A1: per-block region histogram (LDS) + streaming zero of grid B ----
__launch_bounds__(BLK)
__global__ void k_histA(const float* __restrict__ X, int n, int* __restrict__ blockHist,
                        float4* __restrict__ zeroB) {
    __shared__ int h[NREG];
    for (int i = threadIdx.x; i < NREG; i += blockDim.x) h[i] = 0;
    __syncthreads();
    int stride = gridDim.x * blockDim.x;
    for (int i = blockIdx.x * blockDim.x + threadIdx.x; i < n; i += stride) {
        float x = X[3 * i + 0], y = X[3 * i + 1], z = X[3 * i + 2];
        atomicAdd(&h[regOf(binf(x), binf(y), binf(z))], 1);
    }
    __syncthreads();
    for (int i = threadIdx.x; i < NREG; i += blockDim.x)
        blockHist[blockIdx.x * NREG + i] = h[i];
    for (int i = blockIdx.x * blockDim.x + threadIdx.x; i < CELLS; i += stride)
        zeroB[i] = make_float4(0.f, 0.f, 0.f, 0.f);
}

// ---- pass A2: per-region column scan over blocks; regionPS[r] = region total ----
__global__ void k_colscan(int* __restrict__ blockHist, int* __restrict__ regionPS) {
    int r = blockIdx.x * blockDim.x + threadIdx.x;
    if (r >= NREG) return;
    int run = 0;
    for (int b = 0; b < NB_A; ++b) {
        int idx = b * NREG + r;
        int v = blockHist[idx];
        blockHist[idx] = run;   // exclusive within-region block base
        run += v;
    }
    regionPS[r] = run;          // region total (prefixed by k_regprefix)
}

// ---- pass A3: exclusive prefix over 4096 region totals (one block) ----
__launch_bounds__(1024)
__global__ void k_regprefix(int* __restrict__ regionPS) {
    __shared__ int buf[1024];
    int t = threadIdx.x;
    int v0 = regionPS[4 * t + 0], v1 = regionPS[4 * t + 1];
    int v2 = regionPS[4 * t + 2], v3 = regionPS[4 * t + 3];
    int s = v0 + v1 + v2 + v3;
    buf[t] = s;
    __syncthreads();
    for (int d = 1; d < 1024; d <<= 1) {
        int add = (t >= d) ? buf[t - d] : 0;
        __syncthreads();
        buf[t] += add;
        __syncthreads();
    }
    int excl = buf[t] - s;
    regionPS[4 * t + 0] = excl;
    regionPS[4 * t + 1] = excl + v0;
    regionPS[4 * t + 2] = excl + v0 + v1;
    regionPS[4 * t + 3] = excl + v0 + v1 + v2;
    if (t == 1023) regionPS[4096] = buf[1023];
}

// ---- pass A4: scatter points into region buckets (LDS rank, no global atomics) ----
__launch_bounds__(BLK)
__global__ void k_scatterA(const float* __restrict__ X, int n,
                           const int* __restrict__ blockHist,
                           const int* __restrict__ regionPS,
                           float4* __restrict__ bucket) {
    __shared__ int cur[NREG];
    for (int i = threadIdx.x; i < NREG; i += blockDim.x) cur[i] = 0;
    __syncthreads();
    int stride = gridDim.x * blockDim.x;
    for (int i = blockIdx.x * blockDim.x + threadIdx.x; i < n; i += stride) {
        float x = X[3 * i + 0], y = X[3 * i + 1], z = X[3 * i + 2];
        int r = regOf(binf(x), binf(y), binf(z));
        int pos = regionPS[r] + blockHist[blockIdx.x * NREG + r] + atomicAdd(&cur[r], 1);
        bucket[pos] = make_float4(x, y, z, __int_as_float(i));
    }
}

// ---- pass B: one block per region — LDS cell accumulate, plain stores to A,
//      fused compact (E0) + PIdx point->entry ----
__launch_bounds__(BLK)
__global__ void k_binB(const float4* __restrict__ bucket, const int* __restrict__ regionPS,
                       float4* __restrict__ A, int* __restrict__ E0,
                       int* __restrict__ PIdx, int* __restrict__ gM0) {
    __shared__ float4 acc[RC3];
    __shared__ int cidx[RC3];
    __shared__ int cnt, cur, sBase;
    int r = blockIdx.x;
    for (int c = threadIdx.x; c < RC3; c += blockDim.x)
        acc[c] = make_float4(0.f, 0.f, 0.f, 0.f);
    if (threadIdx.x == 0) { cnt = 0; cur = 0; }
    __syncthreads();
    int start = regionPS[r], end = regionPS[r + 1];
    for (int i = start + threadIdx.x; i < end; i += blockDim.x) {
        float4 p = bucket[i];
        int lc = lcOf(binf(p.x), binf(p.y), binf(p.z));
        float* a = (float*)&acc[lc];
        atomicAdd(a + 0, p.x);
        atomicAdd(a + 1, p.y);
        atomicAdd(a + 2, p.z);
        atomicAdd(a + 3, 1.0f);
    }
    __syncthreads();
    int myc = 0;
    for (int c = threadIdx.x; c < RC3; c += blockDim.x)
        if (acc[c].w > 0.f) ++myc;
    if (myc) atomicAdd(&cnt, myc);
    __syncthreads();
    if (threadIdx.x == 0 && cnt > 0) sBase = atomicAdd(gM0, cnt);
    __syncthreads();
    int rx = r / (RDIM * RDIM), ry = (r / RDIM) % RDIM, rz = r % RDIM;
    for (int c = threadIdx.x; c < RC3; c += blockDim.x) {
        if (acc[c].w > 0.f) {
            int idx = sBase + atomicAdd(&cur, 1);
            cidx[c] = idx;
            int bx = rx * RC + c / (RC * RC);
            int by = ry * RC + (c / RC) % RC;
            int bz = rz * RC + c % RC;
            int b = flatb(bx, by, bz);
            E0[idx] = b;
            A[b] = acc[c];
        }
    }
    __syncthreads();
    for (int i = start + threadIdx.x; i < end; i += blockDim.x) {
        float4 p = bucket[i];
        int lc = lcOf(binf(p.x), binf(p.y), binf(p.z));
        PIdx[__float_as_int(p.w)] = cidx[lc];
    }
}

// ---- fused per-step kernel (conv / upd / clear / mask-zero / grid-zero) ----
__launch_bounds__(BLK)
__global__ void k_fused(
    const float4* __restrict__ src, const int* __restrict__ list, const int* __restrict__ pK,
    float4* __restrict__ REo, int* __restrict__ IDXo, float4* __restrict__ eposInit,
    float4* __restrict__ tgt, unsigned* __restrict__ clT,
    int* __restrict__ listOut, int* __restrict__ pKout,
    int updS, const float* __restrict__ X, int n, const int* __restrict__ PIdx,
    const float4* __restrict__ REp, const int* __restrict__ IDXp,
    const int* __restrict__ pM0, float4* __restrict__ epos,
    unsigned* __restrict__ notConv,
    const int* __restrict__ clearList, const int* __restrict__ pKc,
    float4* __restrict__ clearGrid,
    unsigned* __restrict__ zeroMask, int zmW,
    float4* __restrict__ zeroGrid, int zgC) {
    __shared__ unsigned sFlag;
    if (threadIdx.x == 0) sFlag = 0;
    __syncthreads();
    int K = *pK;
    int U = (updS > 0) ? (X ? n : *pM0) : 0;
    int CL = clearList ? *pKc : 0;
    int total = K + U + CL + zmW + zgC;
    bool done = false;
    if (updS > 1) {
        for (int t = 1; t < updS; ++t) done |= (notConv[t] == 0u);
    }
    int lane = threadIdx.x & 63;
    bool moved = false;
    int stride = gridDim.x * blockDim.x;
    for (int idx = blockIdx.x * blockDim.x + threadIdx.x; idx < total; idx += stride) {
        if (idx < K) {
            int b = list[idx];
            int bx = b / DIM2, rem = b % DIM2;
            int by = rem / DIM, bz = rem % DIM;
            float4 np = conv5(src, bx, by, bz);
            REo[idx] = np;
            IDXo[b] = idx;
            if (eposInit) eposInit[idx] = np;
            if (tgt) {
                int bn = flatb(binf(np.x), binf(np.y), binf(np.z));
                float* cell = (float*)&tgt[bn];
                pk_add(cell + 0, np.w * np.x, np.w * np.y);
                pk_add(cell + 2, np.w * np.z, np.w);
                unsigned old = atomicOr(&clT[(unsigned)bn >> 5], 1u << (bn & 31));
                bool isNew = !(old & (1u << (bn & 31)));
                unsigned long long m = __ballot(isNew);
                if (m) {
                    int leader = (int)__ffsll((long long)m) - 1;
                    int base;
                    if (lane == leader) base = atomicAdd(pKout, __popcll(m));
                    base = __shfl(base, leader, 64);
                    if (isNew) listOut[base + __popcll(m & ((1ull << lane) - 1))] = bn;
                }
            }
        } else if (idx < K + U) {
            int e = idx - K;
            if (X) {  // per-point step-1 convergence via PIdx (single gather)
                float x = X[3 * e + 0], y = X[3 * e + 1], z = X[3 * e + 2];
                float4 rr = REp[PIdx[e]];
                float ex = rr.x - x, ey = rr.y - y, ez = rr.z - z;
                moved |= (fmaf(ex, ex, fmaf(ey, ey, ez * ez)) > TOL2);
            } else if (!done) {  // per-entry update to step-updS position
                float4 p = epos[e];
                int j = IDXp[flatb(binf(p.x), binf(p.y), binf(p.z))];
                float4 rr = REp[j];
                float ex = rr.x - p.x, ey = rr.y - p.y, ez = rr.z - p.z;
                moved |= (fmaf(ex, ex, fmaf(ey, ey, ez * ez)) > TOL2);
                epos[e] = make_float4(rr.x, rr.y, rr.z, p.w);
            }
        } else if (idx < K + U + CL) {
            clearGrid[clearList[idx - K - U]] = make_float4(0.f, 0.f, 0.f, 0.f);
        } else if (idx < K + U + CL + zmW) {
            zeroMask[idx - K - U - CL] = 0u;
        } else {
            zeroGrid[idx - K - U - CL - zmW] = make_float4(0.f, 0.f, 0.f, 0.f);
        }
    }
    if (moved) sFlag = 1;
    __syncthreads();
    if (threadIdx.x == 0 && updS > 0 && sFlag) notConv[updS] = 1u;
}

// ---- finalize: per-entry final position table fpos[e] (freeze-aware step-5) ----
__launch_bounds__(BLK)
__global__ void k_fin(const float4* __restrict__ REa, const int* __restrict__ IDXa,
                      const float4* __restrict__ epos, const int* __restrict__ pM0,
                      const unsigned* __restrict__ notConv, float4* __restrict__ fpos) {
    int M0 = *pM0;
    bool done = false;
    for (int t = 1; t <= 4; ++t) done |= (notConv[t] == 0u);
    for (int e = blockIdx.x * blockDim.x + threadIdx.x; e < M0;
         e += gridDim.x * blockDim.x) {
        float4 p = epos[e];
        if (!done) {
            float4 rr = REa[IDXa[flatb(binf(p.x), binf(p.y), binf(p.z))]];
            p.x = rr.x; p.y = rr.y; p.z = rr.z;
        }
        fpos[e] = p;
    }
}

// ---- per-point output: single gather through fpos via PIdx ----
__global__ void k_map(const int* __restrict__ PIdx, int n, const float4* __restrict__ fpos,
                      float* __restrict__ out) {
    int i = blockIdx.x * blockDim.x + threadIdx.x;
    if (i >= n) return;
    float4 p = fpos[PIdx[i]];
    out[3 * i + 0] = p.x;
    out[3 * i + 1] = p.y;
    out[3 * i + 2] = p.z;
}

extern "C" void kernel_launch(void* const* d_in, const int* in_sizes, int n_in,
                              void* d_out, int out_size, void* d_ws, size_t ws_size,
                              hipStream_t stream) {
    const float* X = (const float*)d_in[0];
    int n = in_sizes[0] / 3;

    // ws layout (~98 MB): meta(256) | m0,m1 | A,B,C | IDXa,IDXb | REa,REb,epos |
    // E0,La,Lb,Lc,PIdx | bucket | blockHist | regionPS
    char* ws = (char*)d_ws;
    int*      cnt     = (int*)ws;        // cnt[1..5] list sizes
    unsigned* notConv = (unsigned*)(ws + 32);
    size_t mB = (size_t)CLW * 4;
    size_t gB = (size_t)CELLS * 16;
    unsigned* m0 = (unsigned*)(ws + 256);
    unsigned* m1 = (unsigned*)(ws + 256 + mB);
    float4* A = (float4*)(ws + 256 + 2 * mB);
    float4* B = (float4*)((char*)A + gB);
    float4* C = (float4*)((char*)B + gB);
    int* IDXa = (int*)((char*)C + gB);
    int* IDXb = IDXa + CELLS;
    float4* REa  = (float4*)(IDXb + CELLS);
    float4* REb  = REa + n;
    float4* epos = REb + n;
    int* E0   = (int*)(epos + n);
    int* La   = E0 + n;
    int* Lb   = La + n;
    int* Lc   = Lb + n;
    int* PIdx = Lc + n;
    float4* bucket = (float4*)(PIdx + n);
    int* blockHist = (int*)(bucket + n);
    int* regionPS  = blockHist + NB_A * NREG;   // NREG+1 ints

    // zero: meta + masks + A (B in histA, C in F1; rest write-before-read)
    hipMemsetAsync(ws, 0, 256 + 2 * mB + gB, stream);

    // front end: counting sort by region + LDS bin accumulate + fused compact
    k_histA<<<NB_A, BLK, 0, stream>>>(X, n, blockHist, B);
    k_colscan<<<NREG / BLK, BLK, 0, stream>>>(blockHist, regionPS);
    k_regprefix<<<1, 1024, 0, stream>>>(regionPS);
    k_scatterA<<<NB_A, BLK, 0, stream>>>(X, n, blockHist, regionPS, bucket);
    k_binB<<<NREG, BLK, 0, stream>>>(bucket, regionPS, A, E0, PIdx, &cnt[1]);

    // F1 (step 1): conv A/E0 -> REa/IDXa, epos init; scatter->B (m0 -> La); zero C
    k_fused<<<1024, BLK, 0, stream>>>(A, E0, &cnt[1], REa, IDXa, epos,
                                      B, m0, La, &cnt[2],
                                      0, nullptr, n, nullptr, nullptr, nullptr, nullptr,
                                      nullptr, notConv, nullptr, nullptr, nullptr,
                                      nullptr, 0, C, CELLS);
    // F2 (step 2): conv B/La -> REb/IDXb; scatter->C (m1 -> Lb); upd1 via PIdx;
    //              clear A via E0; zero m0
    k_fused<<<1024, BLK, 0, stream>>>(B, La, &cnt[2], REb, IDXb, nullptr,
                                      C, m1, Lb, &cnt[3],
                                      1, X, n, PIdx, REa, IDXa, &cnt[1], nullptr,
                                      notConv, E0, &cnt[1], A,
                                      m0, CLW, nullptr, 0);
    // F3 (step 3): conv C/Lb -> REa/IDXa; scatter->A (m0 -> Lc); upd2 (REb/IDXb);
    //              clear B via La; zero m1
    k_fused<<<1024, BLK, 0, stream>>>(C, Lb, &cnt[3], REa, IDXa, nullptr,
                                      A, m0, Lc, &cnt[4],
                                      2, nullptr, n, nullptr, REb, IDXb, &cnt[1], epos,
                                      notConv, La, &cnt[2], B,
                                      m1, CLW, nullptr, 0);
    // F4 (step 4): conv A/Lc -> REb/IDXb; scatter->B (m1 -> La); upd3 (REa/IDXa)
    k_fused<<<1024, BLK, 0, stream>>>(A, Lc, &cnt[4], REb, IDXb, nullptr,
                                      B, m1, La, &cnt[5],
                                      3, nullptr, n, nullptr, REa, IDXa, &cnt[1], epos,
                                      notConv, nullptr, nullptr, nullptr,
                                      nullptr, 0, nullptr, 0);
    // F5 (step 5): conv B/La -> REa/IDXa (conv only); upd4 (REb/IDXb)
    k_fused<<<1024, BLK, 0, stream>>>(B, La, &cnt[5], REa, IDXa, nullptr,
                                      nullptr, nullptr, nullptr, nullptr,
                                      4, nullptr, n, nullptr, REb, IDXb, &cnt[1], epos,
                                      notConv, nullptr, nullptr, nullptr,
                                      nullptr, 0, nullptr, 0);

    // finalize per-entry table (fpos reuses REb — free after F5), then map
    k_fin<<<256, BLK, 0, stream>>>(REa, IDXa, epos, &cnt[1], notConv, REb);
    k_map<<<(n + BLK - 1) / BLK, BLK, 0, stream>>>(PIdx, n, REb, (float*)d_out);
}

// Round 7
// 322.221 us; speedup vs baseline: 1.0986x; 1.0986x over previous
//
#include <hip/hip_runtime.h>

// MeanShift++ dense-grid, distinct-bin formulation, v5.
// Identity 1: ref pipeline == 5-tap triangular conv [1,2,3,2,1]^3 over per-bin
// sums/counts. Identity 2: result depends only on bin => per-step work is per
// OCCUPIED BIN (shrinking); per-point state via 1-tap lookups.
// v5 (vs v4): k_binB accumulates in LDS with HW int atomics — u64 fixed-point
// (scale 2^24, wraparound signed) for x/y/z + u32 count — instead of float
// atomicAdd (CAS-loop on LDS without unsafe-fp-atomics => retry storms on the
// ~13-way contended center cells). Quantization error ~1e-7 << 9.25e-2 thresh.

constexpr float BW   = 0.1f;
constexpr float TOL2 = 1e-6f;            // (1e-3)^2
constexpr int DIM  = 112, OFF = 56;      // bins in [-56,55]; |x|<5.6 covered
constexpr int DIM2 = DIM * DIM;
constexpr int CELLS = DIM * DIM * DIM;   // 1,404,928
constexpr int CLW = CELLS / 32;
constexpr int RDIM = 16, RC = 7;         // 16^3 regions of 7^3 cells (112=16*7)
constexpr int NREG = RDIM * RDIM * RDIM; // 4096
constexpr int RC3 = RC * RC * RC;        // 343
constexpr int NB_A = 128, BLK = 256;     // histA/scatterA must share partition
constexpr float FPS = 16777216.0f;       // 2^24 fixed-point scale
constexpr double FPSI = 1.0 / 16777216.0;

typedef float vf2 __attribute__((ext_vector_type(2)));

__device__ __forceinline__ int clampb(int v) { return v < 0 ? 0 : (v > DIM - 1 ? DIM - 1 : v); }
__device__ __forceinline__ int binf(float v) { return clampb((int)(v / BW) + OFF); }  // IEEE div+trunc == ref
__device__ __forceinline__ int flatb(int bx, int by, int bz) { return (bx * DIM + by) * DIM + bz; }
__device__ __forceinline__ int regOf(int bx, int by, int bz) {
    return ((bx / RC) * RDIM + (by / RC)) * RDIM + (bz / RC);
}
__device__ __forceinline__ int lcOf(int bx, int by, int bz) {
    return ((bx % RC) * RC + (by % RC)) * RC + (bz % RC);
}

__device__ __forceinline__ void pk_add(float* p, float a, float b) {
#if defined(__has_builtin) && __has_builtin(__builtin_amdgcn_global_atomic_fadd_v2f32)
    vf2 v = {a, b};
    __builtin_amdgcn_global_atomic_fadd_v2f32((vf2*)p, v);
#else
    atomicAdd(p, a);
    atomicAdd(p + 1, b);
#endif
}

// 5x5x5 triangular conv [1,2,3,2,1]^3; returns (nx,ny,nz, W=center count)
__device__ __forceinline__ float4 conv5(const float4* __restrict__ g, int bx, int by, int bz) {
    const float t[5] = {1.f, 2.f, 3.f, 2.f, 1.f};
    float sx = 0.f, sy = 0.f, sz = 0.f, sc = 0.f, W = 0.f;
    if (bx >= 2 && bx <= DIM - 3 && by >= 2 && by <= DIM - 3 && bz >= 2 && bz <= DIM - 3) {
        #pragma unroll
        for (int dx = 0; dx < 5; ++dx) {
            float wx = t[dx];
            #pragma unroll
            for (int dy = 0; dy < 5; ++dy) {
                float wxy = wx * t[dy];
                const float4* row = g + flatb(bx + dx - 2, by + dy - 2, bz - 2);
                #pragma unroll
                for (int dz = 0; dz < 5; ++dz) {
                    float w = wxy * t[dz];
                    float4 e = row[dz];
                    sx = fmaf(w, e.x, sx);
                    sy = fmaf(w, e.y, sy);
                    sz = fmaf(w, e.z, sz);
                    sc = fmaf(w, e.w, sc);
                    if (dx == 2 && dy == 2 && dz == 2) W = e.w;
                }
            }
        }
    } else {
        for (int dx = -2; dx <= 2; ++dx) {
            int ix = bx + dx; if ((unsigned)ix >= (unsigned)DIM) continue;
            float wx = t[dx + 2];
            for (int dy = -2; dy <= 2; ++dy) {
                int iy = by + dy; if ((unsigned)iy >= (unsigned)DIM) continue;
                float wxy = wx * t[dy + 2];
                for (int dz = -2; dz <= 2; ++dz) {
                    int iz = bz + dz; if ((unsigned)iz >= (unsigned)DIM) continue;
                    float w = wxy * t[dz + 2];
                    float4 e = g[flatb(ix, iy, iz)];
                    sx = fmaf(w, e.x, sx);
                    sy = fmaf(w, e.y, sy);
                    sz = fmaf(w, e.z, sz);
                    sc = fmaf(w, e.w, sc);
                    if (dx == 0 && dy == 0 && dz == 0) W = e.w;
                }
            }
        }
    }
    return make_float4(sx / sc, sy / sc, sz / sc, W);
}

// ---- pass A1: per-block region histogram (LDS) + streaming zero of grid B ----
__launch_bounds__(BLK)
__global__ void k_histA(const float* __restrict__ X, int n, int* __restrict__ blockHist,
                        float4* __restrict__ zeroB) {
    __shared__ int h[NREG];
    for (int i = threadIdx.x; i < NREG; i += blockDim.x) h[i] = 0;
    __syncthreads();
    int stride = gridDim.x * blockDim.x;
    for (int i = blockIdx.x * blockDim.x + threadIdx.x; i < n; i += stride) {
        float x = X[3 * i + 0], y = X[3 * i + 1], z = X[3 * i + 2];
        atomicAdd(&h[regOf(binf(x), binf(y), binf(z))], 1);
    }
    __syncthreads();
    for (int i = threadIdx.x; i < NREG; i += blockDim.x)
        blockHist[blockIdx.x * NREG + i] = h[i];
    for (int i = blockIdx.x * blockDim.x + threadIdx.x; i < CELLS; i += stride)
        zeroB[i] = make_float4(0.f, 0.f, 0.f, 0.f);
}

// ---- pass A2: per-region column scan over blocks; regionPS[r] = region total ----
__global__ void k_colscan(int* __restrict__ blockHist, int* __restrict__ regionPS) {
    int r = blockIdx.x * blockDim.x + threadIdx.x;
    if (r >= NREG) return;
    int run = 0;
    for (int b = 0; b < NB_A; ++b) {
        int idx = b * NREG + r;
        int v = blockHist[idx];
        blockHist[idx] = run;   // exclusive within-region block base
        run += v;
    }
    regionPS[r] = run;          // region total (prefixed by k_regprefix)
}

// ---- pass A3: exclusive prefix over 4096 region totals (one block) ----
__launch_bounds__(1024)
__global__ void k_regprefix(int* __restrict__ regionPS) {
    __shared__ int buf[1024];
    int t = threadIdx.x;
    int v0 = regionPS[4 * t + 0], v1 = regionPS[4 * t + 1];
    int v2 = regionPS[4 * t + 2], v3 = regionPS[4 * t + 3];
    int s = v0 + v1 + v2 + v3;
    buf[t] = s;
    __syncthreads();
    for (int d = 1; d < 1024; d <<= 1) {
        int add = (t >= d) ? buf[t - d] : 0;
        __syncthreads();
        buf[t] += add;
        __syncthreads();
    }
    int excl = buf[t] - s;
    regionPS[4 * t + 0] = excl;
    regionPS[4 * t + 1] = excl + v0;
    regionPS[4 * t + 2] = excl + v0 + v1;
    regionPS[4 * t + 3] = excl + v0 + v1 + v2;
    if (t == 1023) regionPS[4096] = buf[1023];
}

// ---- pass A4: scatter points into region buckets (LDS rank, no global atomics) ----
__launch_bounds__(BLK)
__global__ void k_scatterA(const float* __restrict__ X, int n,
                           const int* __restrict__ blockHist,
                           const int* __restrict__ regionPS,
                           float4* __restrict__ bucket) {
    __shared__ int cur[NREG];
    for (int i = threadIdx.x; i < NREG; i += blockDim.x) cur[i] = 0;
    __syncthreads();
    int stride = gridDim.x * blockDim.x;
    for (int i = blockIdx.x * blockDim.x + threadIdx.x; i < n; i += stride) {
        float x = X[3 * i + 0], y = X[3 * i + 1], z = X[3 * i + 2];
        int r = regOf(binf(x), binf(y), binf(z));
        int pos = regionPS[r] + blockHist[blockIdx.x * NREG + r] + atomicAdd(&cur[r], 1);
        bucket[pos] = make_float4(x, y, z, __int_as_float(i));
    }
}

// ---- pass B: one block per region — LDS int-atomic cell accumulate (fixed-point
//      u64 for x/y/z, u32 count), plain stores to A, fused compact (E0) + PIdx ----
__launch_bounds__(BLK)
__global__ void k_binB(const float4* __restrict__ bucket, const int* __restrict__ regionPS,
                       float4* __restrict__ A, int* __restrict__ E0,
                       int* __restrict__ PIdx, int* __restrict__ gM0) {
    __shared__ unsigned long long aX[RC3], aY[RC3], aZ[RC3];
    __shared__ unsigned aC[RC3];
    __shared__ int cidx[RC3];
    __shared__ int cnt, cur, sBase;
    int r = blockIdx.x;
    for (int c = threadIdx.x; c < RC3; c += blockDim.x) {
        aX[c] = 0ull; aY[c] = 0ull; aZ[c] = 0ull; aC[c] = 0u;
    }
    if (threadIdx.x == 0) { cnt = 0; cur = 0; }
    __syncthreads();
    int start = regionPS[r], end = regionPS[r + 1];
    for (int i = start + threadIdx.x; i < end; i += blockDim.x) {
        float4 p = bucket[i];
        int lc = lcOf(binf(p.x), binf(p.y), binf(p.z));
        // signed fixed-point via two's-complement wraparound on u64
        atomicAdd(&aX[lc], (unsigned long long)(long long)rintf(p.x * FPS));
        atomicAdd(&aY[lc], (unsigned long long)(long long)rintf(p.y * FPS));
        atomicAdd(&aZ[lc], (unsigned long long)(long long)rintf(p.z * FPS));
        atomicAdd(&aC[lc], 1u);
    }
    __syncthreads();
    int myc = 0;
    for (int c = threadIdx.x; c < RC3; c += blockDim.x)
        if (aC[c] > 0u) ++myc;
    if (myc) atomicAdd(&cnt, myc);
    __syncthreads();
    if (threadIdx.x == 0 && cnt > 0) sBase = atomicAdd(gM0, cnt);
    __syncthreads();
    int rx = r / (RDIM * RDIM), ry = (r / RDIM) % RDIM, rz = r % RDIM;
    for (int c = threadIdx.x; c < RC3; c += blockDim.x) {
        if (aC[c] > 0u) {
            int idx = sBase + atomicAdd(&cur, 1);
            cidx[c] = idx;
            int bx = rx * RC + c / (RC * RC);
            int by = ry * RC + (c / RC) % RC;
            int bz = rz * RC + c % RC;
            int b = flatb(bx, by, bz);
            E0[idx] = b;
            A[b] = make_float4((float)((double)(long long)aX[c] * FPSI),
                               (float)((double)(long long)aY[c] * FPSI),
                               (float)((double)(long long)aZ[c] * FPSI),
                               (float)aC[c]);
        }
    }
    __syncthreads();
    for (int i = start + threadIdx.x; i < end; i += blockDim.x) {
        float4 p = bucket[i];
        int lc = lcOf(binf(p.x), binf(p.y), binf(p.z));
        PIdx[__float_as_int(p.w)] = cidx[lc];
    }
}

// ---- fused per-step kernel (conv / upd / clear / mask-zero / grid-zero) ----
__launch_bounds__(BLK)
__global__ void k_fused(
    const float4* __restrict__ src, const int* __restrict__ list, const int* __restrict__ pK,
    float4* __restrict__ REo, int* __restrict__ IDXo, float4* __restrict__ eposInit,
    float4* __restrict__ tgt, unsigned* __restrict__ clT,
    int* __restrict__ listOut, int* __restrict__ pKout,
    int updS, const float* __restrict__ X, int n, const int* __restrict__ PIdx,
    const float4* __restrict__ REp, const int* __restrict__ IDXp,
    const int* __restrict__ pM0, float4* __restrict__ epos,
    unsigned* __restrict__ notConv,
    const int* __restrict__ clearList, const int* __restrict__ pKc,
    float4* __restrict__ clearGrid,
    unsigned* __restrict__ zeroMask, int zmW,
    float4* __restrict__ zeroGrid, int zgC) {
    __shared__ unsigned sFlag;
    if (threadIdx.x == 0) sFlag = 0;
    __syncthreads();
    int K = *pK;
    int U = (updS > 0) ? (X ? n : *pM0) : 0;
    int CL = clearList ? *pKc : 0;
    int total = K + U + CL + zmW + zgC;
    bool done = false;
    if (updS > 1) {
        for (int t = 1; t < updS; ++t) done |= (notConv[t] == 0u);
    }
    int lane = threadIdx.x & 63;
    bool moved = false;
    int stride = gridDim.x * blockDim.x;
    for (int idx = blockIdx.x * blockDim.x + threadIdx.x; idx < total; idx += stride) {
        if (idx < K) {
            int b = list[idx];
            int bx = b / DIM2, rem = b % DIM2;
            int by = rem / DIM, bz = rem % DIM;
            float4 np = conv5(src, bx, by, bz);
            REo[idx] = np;
            IDXo[b] = idx;
            if (eposInit) eposInit[idx] = np;
            if (tgt) {
                int bn = flatb(binf(np.x), binf(np.y), binf(np.z));
                float* cell = (float*)&tgt[bn];
                pk_add(cell + 0, np.w * np.x, np.w * np.y);
                pk_add(cell + 2, np.w * np.z, np.w);
                unsigned old = atomicOr(&clT[(unsigned)bn >> 5], 1u << (bn & 31));
                bool isNew = !(old & (1u << (bn & 31)));
                unsigned long long m = __ballot(isNew);
                if (m) {
                    int leader = (int)__ffsll((long long)m) - 1;
                    int base;
                    if (lane == leader) base = atomicAdd(pKout, __popcll(m));
                    base = __shfl(base, leader, 64);
                    if (isNew) listOut[base + __popcll(m & ((1ull << lane) - 1))] = bn;
                }
            }
        } else if (idx < K + U) {
            int e = idx - K;
            if (X) {  // per-point step-1 convergence via PIdx (single gather)
                float x = X[3 * e + 0], y = X[3 * e + 1], z = X[3 * e + 2];
                float4 rr = REp[PIdx[e]];
                float ex = rr.x - x, ey = rr.y - y, ez = rr.z - z;
                moved |= (fmaf(ex, ex, fmaf(ey, ey, ez * ez)) > TOL2);
            } else if (!done) {  // per-entry update to step-updS position
                float4 p = epos[e];
                int j = IDXp[flatb(binf(p.x), binf(p.y), binf(p.z))];
                float4 rr = REp[j];
                float ex = rr.x - p.x, ey = rr.y - p.y, ez = rr.z - p.z;
                moved |= (fmaf(ex, ex, fmaf(ey, ey, ez * ez)) > TOL2);
                epos[e] = make_float4(rr.x, rr.y, rr.z, p.w);
            }
        } else if (idx < K + U + CL) {
            clearGrid[clearList[idx - K - U]] = make_float4(0.f, 0.f, 0.f, 0.f);
        } else if (idx < K + U + CL + zmW) {
            zeroMask[idx - K - U - CL] = 0u;
        } else {
            zeroGrid[idx - K - U - CL - zmW] = make_float4(0.f, 0.f, 0.f, 0.f);
        }
    }
    if (moved) sFlag = 1;
    __syncthreads();
    if (threadIdx.x == 0 && updS > 0 && sFlag) notConv[updS] = 1u;
}

// ---- finalize: per-entry final position table fpos[e] (freeze-aware step-5) ----
__launch_bounds__(BLK)
__global__ void k_fin(const float4* __restrict__ REa, const int* __restrict__ IDXa,
                      const float4* __restrict__ epos, const int* __restrict__ pM0,
                      const unsigned* __restrict__ notConv, float4* __restrict__ fpos) {
    int M0 = *pM0;
    bool done = false;
    for (int t = 1; t <= 4; ++t) done |= (notConv[t] == 0u);
    for (int e = blockIdx.x * blockDim.x + threadIdx.x; e < M0;
         e += gridDim.x * blockDim.x) {
        float4 p = epos[e];
        if (!done) {
            float4 rr = REa[IDXa[flatb(binf(p.x), binf(p.y), binf(p.z))]];
            p.x = rr.x; p.y = rr.y; p.z = rr.z;
        }
        fpos[e] = p;
    }
}

// ---- per-point output: single gather through fpos via PIdx ----
__global__ void k_map(const int* __restrict__ PIdx, int n, const float4* __restrict__ fpos,
                      float* __restrict__ out) {
    int i = blockIdx.x * blockDim.x + threadIdx.x;
    if (i >= n) return;
    float4 p = fpos[PIdx[i]];
    out[3 * i + 0] = p.x;
    out[3 * i + 1] = p.y;
    out[3 * i + 2] = p.z;
}

extern "C" void kernel_launch(void* const* d_in, const int* in_sizes, int n_in,
                              void* d_out, int out_size, void* d_ws, size_t ws_size,
                              hipStream_t stream) {
    const float* X = (const float*)d_in[0];
    int n = in_sizes[0] / 3;

    // ws layout (~98 MB): meta(256) | m0,m1 | A,B,C | IDXa,IDXb | REa,REb,epos |
    // E0,La,Lb,Lc,PIdx | bucket | blockHist | regionPS
    char* ws = (char*)d_ws;
    int*      cnt     = (int*)ws;        // cnt[1..5] list sizes
    unsigned* notConv = (unsigned*)(ws + 32);
    size_t mB = (size_t)CLW * 4;
    size_t gB = (size_t)CELLS * 16;
    unsigned* m0 = (unsigned*)(ws + 256);
    unsigned* m1 = (unsigned*)(ws + 256 + mB);
    float4* A = (float4*)(ws + 256 + 2 * mB);
    float4* B = (float4*)((char*)A + gB);
    float4* C = (float4*)((char*)B + gB);
    int* IDXa = (int*)((char*)C + gB);
    int* IDXb = IDXa + CELLS;
    float4* REa  = (float4*)(IDXb + CELLS);
    float4* REb  = REa + n;
    float4* epos = REb + n;
    int* E0   = (int*)(epos + n);
    int* La   = E0 + n;
    int* Lb   = La + n;
    int* Lc   = Lb + n;
    int* PIdx = Lc + n;
    float4* bucket = (float4*)(PIdx + n);
    int* blockHist = (int*)(bucket + n);
    int* regionPS  = blockHist + NB_A * NREG;   // NREG+1 ints

    // zero: meta + masks + A (B in histA, C in F1; rest write-before-read)
    hipMemsetAsync(ws, 0, 256 + 2 * mB + gB, stream);

    // front end: counting sort by region + LDS int-atomic accumulate + fused compact
    k_histA<<<NB_A, BLK, 0, stream>>>(X, n, blockHist, B);
    k_colscan<<<NREG / BLK, BLK, 0, stream>>>(blockHist, regionPS);
    k_regprefix<<<1, 1024, 0, stream>>>(regionPS);
    k_scatterA<<<NB_A, BLK, 0, stream>>>(X, n, blockHist, regionPS, bucket);
    k_binB<<<NREG, BLK, 0, stream>>>(bucket, regionPS, A, E0, PIdx, &cnt[1]);

    // F1 (step 1): conv A/E0 -> REa/IDXa, epos init; scatter->B (m0 -> La); zero C
    k_fused<<<1024, BLK, 0, stream>>>(A, E0, &cnt[1], REa, IDXa, epos,
                                      B, m0, La, &cnt[2],
                                      0, nullptr, n, nullptr, nullptr, nullptr, nullptr,
                                      nullptr, notConv, nullptr, nullptr, nullptr,
                                      nullptr, 0, C, CELLS);
    // F2 (step 2): conv B/La -> REb/IDXb; scatter->C (m1 -> Lb); upd1 via PIdx;
    //              clear A via E0; zero m0
    k_fused<<<1024, BLK, 0, stream>>>(B, La, &cnt[2], REb, IDXb, nullptr,
                                      C, m1, Lb, &cnt[3],
                                      1, X, n, PIdx, REa, IDXa, &cnt[1], nullptr,
                                      notConv, E0, &cnt[1], A,
                                      m0, CLW, nullptr, 0);
    // F3 (step 3): conv C/Lb -> REa/IDXa; scatter->A (m0 -> Lc); upd2 (REb/IDXb);
    //              clear B via La; zero m1
    k_fused<<<1024, BLK, 0, stream>>>(C, Lb, &cnt[3], REa, IDXa, nullptr,
                                      A, m0, Lc, &cnt[4],
                                      2, nullptr, n, nullptr, REb, IDXb, &cnt[1], epos,
                                      notConv, La, &cnt[2], B,
                                      m1, CLW, nullptr, 0);
    // F4 (step 4): conv A/Lc -> REb/IDXb; scatter->B (m1 -> La); upd3 (REa/IDXa)
    k_fused<<<1024, BLK, 0, stream>>>(A, Lc, &cnt[4], REb, IDXb, nullptr,
                                      B, m1, La, &cnt[5],
                                      3, nullptr, n, nullptr, REa, IDXa, &cnt[1], epos,
                                      notConv, nullptr, nullptr, nullptr,
                                      nullptr, 0, nullptr, 0);
    // F5 (step 5): conv B/La -> REa/IDXa (conv only); upd4 (REb/IDXb)
    k_fused<<<1024, BLK, 0, stream>>>(B, La, &cnt[5], REa, IDXa, nullptr,
                                      nullptr, nullptr, nullptr, nullptr,
                                      4, nullptr, n, nullptr, REb, IDXb, &cnt[1], epos,
                                      notConv, nullptr, nullptr, nullptr,
                                      nullptr, 0, nullptr, 0);

    // finalize per-entry table (fpos reuses REb — free after F5), then map
    k_fin<<<256, BLK, 0, stream>>>(REa, IDXa, epos, &cnt[1], notConv, REb);
    k_map<<<(n + BLK - 1) / BLK, BLK, 0, stream>>>(PIdx, n, REb, (float*)d_out);
}